// Round 2
// baseline (144.719 us; speedup 1.0000x reference)
//
#include <hip/hip_runtime.h>
#include <hip/hip_bf16.h>

// Sizes (fixed by the problem)
#define TT   256   // t
#define BB   8     // batch
#define SS   256   // s
#define DD   512   // QD = KD = VD
#define C2LOG2E 2.8853900817779268f   // 2*log2(e)
#define LOG2E   1.4426950408889634f

// ---------------------------------------------------------------------------
// GEMM: C[m][n] = scale * sum_k A_row(m)[k] * Bm[n*ldb + k]
// M = 2048 (= b*256 + r), N = 512, K = 512.
// A row base = r*strideR + b*strideB  (r = m&255, b = m>>8)
// ---------------------------------------------------------------------------
__global__ __launch_bounds__(256) void gemm_nt(const float* __restrict__ A,
                                               const float* __restrict__ Bm,
                                               float* __restrict__ C,
                                               int strideR, int strideB, int ldb,
                                               float scale) {
    __shared__ __align__(16) float As[16][68];
    __shared__ __align__(16) float Bs[16][68];
    const int tid = threadIdx.x;
    const int tx = tid & 15, ty = tid >> 4;
    const int tileN = blockIdx.x * 64;
    const int tileM = blockIdx.y * 64;

    const int lm = tid >> 2;      // 0..63: row within tile (for staging)
    const int c4 = tid & 3;       // 0..3 : float4 column group

    const int mg = tileM + lm;
    const int r  = mg & 255, bidx = mg >> 8;
    const float* arow = A + (size_t)r * strideR + (size_t)bidx * strideB;
    const float* brow = Bm + (size_t)(tileN + lm) * ldb;

    float acc[4][4] = {};

    for (int kb = 0; kb < DD; kb += 16) {
        float4 av = *(const float4*)(arow + kb + c4 * 4);
        float4 bv = *(const float4*)(brow + kb + c4 * 4);
        __syncthreads();
        As[c4*4+0][lm] = av.x; As[c4*4+1][lm] = av.y;
        As[c4*4+2][lm] = av.z; As[c4*4+3][lm] = av.w;
        Bs[c4*4+0][lm] = bv.x; Bs[c4*4+1][lm] = bv.y;
        Bs[c4*4+2][lm] = bv.z; Bs[c4*4+3][lm] = bv.w;
        __syncthreads();
        #pragma unroll
        for (int kk = 0; kk < 16; ++kk) {
            float4 a4 = *(const float4*)&As[kk][ty * 4];
            float4 b4 = *(const float4*)&Bs[kk][tx * 4];
            float a[4] = {a4.x, a4.y, a4.z, a4.w};
            float b[4] = {b4.x, b4.y, b4.z, b4.w};
            #pragma unroll
            for (int i = 0; i < 4; ++i)
                #pragma unroll
                for (int j = 0; j < 4; ++j)
                    acc[i][j] = fmaf(a[i], b[j], acc[i][j]);
        }
    }
    #pragma unroll
    for (int i = 0; i < 4; ++i) {
        float4 o = make_float4(acc[i][0]*scale, acc[i][1]*scale,
                               acc[i][2]*scale, acc[i][3]*scale);
        *(float4*)(C + (size_t)(tileM + ty*4 + i) * DD + tileN + tx*4) = o;
    }
}

// ---------------------------------------------------------------------------
// Fused: weight (tanh-reduced) -> softmax -> ctx.  One block = (b, 4 t-rows).
// qp2/kp2 are pre-scaled by 2*log2(e) so tanh(y) = 1 - 2*rcp(exp2(x)+1),
// and the constant sum(va) term is dropped (softmax shift-invariant).
// ---------------------------------------------------------------------------
__global__ __launch_bounds__(256) void attn_fused(const float* __restrict__ qp2,
                                                  const float* __restrict__ kp2,
                                                  const float* __restrict__ va,
                                                  const float* __restrict__ values,
                                                  float* __restrict__ out) {
    __shared__ __align__(16) float qp_s[4][512];   // 8 KB
    __shared__ float vb_s[512];                    // 2 KB
    __shared__ float kpT[32][257];                 // 32.9 KB (transposed, +1 pad)
    __shared__ float w_s[4][256];                  // 4 KB (scores for ctx)

    const int tid  = threadIdx.x;
    const int lane = tid & 63;
    const int wid  = tid >> 6;          // wave id 0..3 -> t row
    const int b    = blockIdx.y;
    const int t0   = blockIdx.x * 4;

    // Stage qp rows (4*512 consecutive floats) + vb = -2*va
    {
        const float4* qsrc = (const float4*)(qp2 + (size_t)(b * TT + t0) * DD);
        float4* qdst = (float4*)&qp_s[0][0];
        qdst[tid]       = qsrc[tid];
        qdst[tid + 256] = qsrc[tid + 256];
        vb_s[tid]       = -2.0f * va[tid];
        vb_s[tid + 256] = -2.0f * va[tid + 256];
    }

    float acc0 = 0.f, acc1 = 0.f, acc2 = 0.f, acc3 = 0.f;
    const float* kp2b = kp2 + (size_t)b * SS * DD;

    for (int kc = 0; kc < DD; kc += 32) {
        __syncthreads();
        #pragma unroll
        for (int rr = 0; rr < 8; ++rr) {
            int fid = rr * 256 + tid;     // 0..2047 float4 slots
            int s   = fid >> 3;
            int cc  = fid & 7;
            float4 v = *(const float4*)(kp2b + (size_t)s * DD + kc + cc * 4);
            kpT[cc*4+0][s] = v.x;
            kpT[cc*4+1][s] = v.y;
            kpT[cc*4+2][s] = v.z;
            kpT[cc*4+3][s] = v.w;
        }
        __syncthreads();
        #pragma unroll 8
        for (int kk = 0; kk < 32; ++kk) {
            float qv  = qp_s[wid][kc + kk];   // broadcast
            float vbk = vb_s[kc + kk];        // broadcast
            float k0 = kpT[kk][lane];
            float k1 = kpT[kk][lane + 64];
            float k2 = kpT[kk][lane + 128];
            float k3 = kpT[kk][lane + 192];
            acc0 = fmaf(vbk, __builtin_amdgcn_rcpf(__builtin_amdgcn_exp2f(qv + k0) + 1.0f), acc0);
            acc1 = fmaf(vbk, __builtin_amdgcn_rcpf(__builtin_amdgcn_exp2f(qv + k1) + 1.0f), acc1);
            acc2 = fmaf(vbk, __builtin_amdgcn_rcpf(__builtin_amdgcn_exp2f(qv + k2) + 1.0f), acc2);
            acc3 = fmaf(vbk, __builtin_amdgcn_rcpf(__builtin_amdgcn_exp2f(qv + k3) + 1.0f), acc3);
        }
    }

    // Softmax across s = {lane, lane+64, lane+128, lane+192} within each wave
    float m = fmaxf(fmaxf(acc0, acc1), fmaxf(acc2, acc3));
    #pragma unroll
    for (int off = 32; off > 0; off >>= 1) m = fmaxf(m, __shfl_xor(m, off));
    float p0 = __builtin_amdgcn_exp2f((acc0 - m) * LOG2E);
    float p1 = __builtin_amdgcn_exp2f((acc1 - m) * LOG2E);
    float p2 = __builtin_amdgcn_exp2f((acc2 - m) * LOG2E);
    float p3 = __builtin_amdgcn_exp2f((acc3 - m) * LOG2E);
    float sum = (p0 + p1) + (p2 + p3);
    #pragma unroll
    for (int off = 32; off > 0; off >>= 1) sum += __shfl_xor(sum, off);
    float inv = __builtin_amdgcn_rcpf(sum);
    p0 *= inv; p1 *= inv; p2 *= inv; p3 *= inv;

    w_s[wid][lane]       = p0;
    w_s[wid][lane + 64]  = p1;
    w_s[wid][lane + 128] = p2;
    w_s[wid][lane + 192] = p3;

    {   // score output (f32), row (b, t0+wid)
        float* osc = out + (size_t)(b * TT + t0 + wid) * SS;
        osc[lane]       = p0;
        osc[lane + 64]  = p1;
        osc[lane + 128] = p2;
        osc[lane + 192] = p3;
    }
    __syncthreads();

    // ctx[t, v] = sum_s score[t][s] * values[b][s][v]; thread owns v = tid, tid+256
    const float* vbase = values + (size_t)b * SS * DD;
    float c0[4] = {0.f, 0.f, 0.f, 0.f};
    float c1[4] = {0.f, 0.f, 0.f, 0.f};
    #pragma unroll 4
    for (int s = 0; s < SS; ++s) {
        float a0 = vbase[(size_t)s * DD + tid];
        float a1 = vbase[(size_t)s * DD + tid + 256];
        #pragma unroll
        for (int t = 0; t < 4; ++t) {
            float sc = w_s[t][s];
            c0[t] = fmaf(sc, a0, c0[t]);
            c1[t] = fmaf(sc, a1, c1[t]);
        }
    }
    float* octx = out + (size_t)BB * TT * SS;
    #pragma unroll
    for (int t = 0; t < 4; ++t) {
        size_t rowo = (size_t)(b * TT + t0 + t) * DD;
        octx[rowo + tid]       = c0[t];
        octx[rowo + tid + 256] = c1[t];
    }
}

// ---------------------------------------------------------------------------
extern "C" void kernel_launch(void* const* d_in, const int* in_sizes, int n_in,
                              void* d_out, int out_size, void* d_ws, size_t ws_size,
                              hipStream_t stream) {
    const float* query  = (const float*)d_in[0];  // (T,B,QD)
    const float* keys   = (const float*)d_in[1];  // (B,S,KD)
    const float* values = (const float*)d_in[2];  // (B,S,VD)
    const float* Wa     = (const float*)d_in[3];  // (KD, QD+KD)
    const float* va     = (const float*)d_in[4];  // (1, KD)
    float* out = (float*)d_out;

    float* qp2 = (float*)d_ws;                    // 2048 x 512 f32 = 4 MB
    float* kp2 = qp2 + (size_t)BB * TT * DD;      // 2048 x 512 f32 = 4 MB

    dim3 gg(DD / 64, (BB * TT) / 64);             // (8, 32)
    // qp'[b*T+t][k] = c * sum_q query[t,b,q] * Wa[k][q]
    gemm_nt<<<gg, 256, 0, stream>>>(query, Wa, qp2,
                                    BB * DD /*t stride*/, DD /*b stride*/,
                                    2 * DD /*ldb*/, C2LOG2E);
    // kp'[b*S+s][h] = c * sum_k keys[b,s,k] * Wa[h][512+k]
    gemm_nt<<<gg, 256, 0, stream>>>(keys, Wa + DD, kp2,
                                    DD /*s stride*/, SS * DD /*b stride*/,
                                    2 * DD /*ldb*/, C2LOG2E);

    attn_fused<<<dim3(TT / 4, BB), 256, 0, stream>>>(qp2, kp2, va, values, out);
}

// Round 3
// 105.369 us; speedup vs baseline: 1.3735x; 1.3735x over previous
//
#include <hip/hip_runtime.h>
#include <hip/hip_bf16.h>

// Sizes (fixed by the problem)
#define TT   256   // t
#define BB   8     // batch
#define SS   256   // s
#define DD   512   // QD = KD = VD
#define C2LOG2E 2.8853900817779268f   // 2*log2(e)
#define LOG2E   1.4426950408889634f

// ---------------------------------------------------------------------------
// Both projection GEMMs in one launch (blockIdx.z: 0 = query, 1 = keys).
// C[m][n] = exp2( scale * sum_k A_row(m)[k] * Wa[n][...k...] )
//   z=0: eq[b*T+t][k]           (row-major, M = b*256+t)
//   z=1: ekT[b][k][s]           (k-major / transposed, M = b*256+s)
// The exp2 lets the attention inner loop use exp2(q+k) = eq*ek.
// ---------------------------------------------------------------------------
__global__ __launch_bounds__(256) void gemm_both(const float* __restrict__ query,
                                                 const float* __restrict__ keys,
                                                 const float* __restrict__ Wa,
                                                 float* __restrict__ eq,
                                                 float* __restrict__ ekT) {
    const bool isQ = (blockIdx.z == 0);
    const float* A  = isQ ? query : keys;
    const float* Bm = isQ ? Wa : (Wa + DD);
    const int strideR = isQ ? BB * DD : DD;       // row step (t or s)
    const int strideB = isQ ? DD : SS * DD;       // batch step
    const int ldb = 2 * DD;

    __shared__ __align__(16) float As[16][68];
    __shared__ __align__(16) float Bs[16][68];
    const int tid = threadIdx.x;
    const int tx = tid & 15, ty = tid >> 4;
    const int tileN = blockIdx.x * 64;
    const int tileM = blockIdx.y * 64;

    const int lm = tid >> 2;      // 0..63: row within tile (staging)
    const int c4 = tid & 3;       // 0..3 : float4 column group

    const int mg = tileM + lm;
    const int r  = mg & 255, bidx = mg >> 8;
    const float* arow = A + (size_t)r * strideR + (size_t)bidx * strideB;
    const float* brow = Bm + (size_t)(tileN + lm) * ldb;

    float acc[4][4] = {};

    for (int kb = 0; kb < DD; kb += 16) {
        float4 av = *(const float4*)(arow + kb + c4 * 4);
        float4 bv = *(const float4*)(brow + kb + c4 * 4);
        __syncthreads();
        As[c4*4+0][lm] = av.x; As[c4*4+1][lm] = av.y;
        As[c4*4+2][lm] = av.z; As[c4*4+3][lm] = av.w;
        Bs[c4*4+0][lm] = bv.x; Bs[c4*4+1][lm] = bv.y;
        Bs[c4*4+2][lm] = bv.z; Bs[c4*4+3][lm] = bv.w;
        __syncthreads();
        #pragma unroll
        for (int kk = 0; kk < 16; ++kk) {
            float4 a4 = *(const float4*)&As[kk][ty * 4];
            float4 b4 = *(const float4*)&Bs[kk][tx * 4];
            float a[4] = {a4.x, a4.y, a4.z, a4.w};
            float b[4] = {b4.x, b4.y, b4.z, b4.w};
            #pragma unroll
            for (int i = 0; i < 4; ++i)
                #pragma unroll
                for (int j = 0; j < 4; ++j)
                    acc[i][j] = fmaf(a[i], b[j], acc[i][j]);
        }
    }

    if (isQ) {
        // eq[m][n], row-major; exp2(scale*acc)
        #pragma unroll
        for (int i = 0; i < 4; ++i) {
            float4 o;
            o.x = __builtin_amdgcn_exp2f(acc[i][0] * C2LOG2E);
            o.y = __builtin_amdgcn_exp2f(acc[i][1] * C2LOG2E);
            o.z = __builtin_amdgcn_exp2f(acc[i][2] * C2LOG2E);
            o.w = __builtin_amdgcn_exp2f(acc[i][3] * C2LOG2E);
            *(float4*)(eq + (size_t)(tileM + ty*4 + i) * DD + tileN + tx*4) = o;
        }
    } else {
        // ekT[b][n][s]: transposed store; i indexes consecutive s
        const int b  = tileM >> 8;
        const int s0 = (tileM & 255) + ty * 4;
        float* base = ekT + (size_t)b * DD * SS;
        #pragma unroll
        for (int j = 0; j < 4; ++j) {
            const int n = tileN + tx * 4 + j;
            float4 o;
            o.x = __builtin_amdgcn_exp2f(acc[0][j] * C2LOG2E);
            o.y = __builtin_amdgcn_exp2f(acc[1][j] * C2LOG2E);
            o.z = __builtin_amdgcn_exp2f(acc[2][j] * C2LOG2E);
            o.w = __builtin_amdgcn_exp2f(acc[3][j] * C2LOG2E);
            *(float4*)(base + (size_t)n * SS + s0) = o;
        }
    }
}

// ---------------------------------------------------------------------------
// Fused attention. One block = (b, 4 t-rows); wave w owns t-row t0+w,
// lane owns s = 4*lane .. 4*lane+3.
// weight[t][s] = const + sum_k vb[k] * rcp(eq[t][k]*ekT[k][s] + 1)
//   (vb = -2*va; const = sum(va) drops in softmax)
// k-loop is barrier-free: ekT rows are coalesced 1KB global loads (L2-hot).
// ---------------------------------------------------------------------------
__global__ __launch_bounds__(256) void attn_fused(const float* __restrict__ eq,
                                                  const float* __restrict__ ekT,
                                                  const float* __restrict__ va,
                                                  const float* __restrict__ values,
                                                  float* __restrict__ out) {
    __shared__ __align__(16) float eq_s[4][512];   // 8 KB
    __shared__ __align__(16) float vb_s[512];      // 2 KB
    __shared__ __align__(16) float w_s[4][256];    // 4 KB

    const int tid  = threadIdx.x;
    const int lane = tid & 63;
    const int wid  = tid >> 6;          // wave id 0..3 -> t row
    const int b    = blockIdx.y;
    const int t0   = blockIdx.x * 4;

    // Stage eq rows (4*512 consecutive floats) + vb = -2*va
    {
        const float4* qsrc = (const float4*)(eq + (size_t)(b * TT + t0) * DD);
        float4* qdst = (float4*)&eq_s[0][0];
        qdst[tid]       = qsrc[tid];
        qdst[tid + 256] = qsrc[tid + 256];
        vb_s[tid]       = -2.0f * va[tid];
        vb_s[tid + 256] = -2.0f * va[tid + 256];
    }
    __syncthreads();

    const float* ekb = ekT + (size_t)b * DD * SS + 4 * lane;

    float acc0 = 0.f, acc1 = 0.f, acc2 = 0.f, acc3 = 0.f;
    #pragma unroll 8
    for (int kk = 0; kk < DD; ++kk) {
        float4 ek = *(const float4*)(ekb + (size_t)kk * SS);
        float eqv = eq_s[wid][kk];
        float vbk = vb_s[kk];
        acc0 = fmaf(vbk, __builtin_amdgcn_rcpf(fmaf(eqv, ek.x, 1.0f)), acc0);
        acc1 = fmaf(vbk, __builtin_amdgcn_rcpf(fmaf(eqv, ek.y, 1.0f)), acc1);
        acc2 = fmaf(vbk, __builtin_amdgcn_rcpf(fmaf(eqv, ek.z, 1.0f)), acc2);
        acc3 = fmaf(vbk, __builtin_amdgcn_rcpf(fmaf(eqv, ek.w, 1.0f)), acc3);
    }

    // Softmax across the wave (lane owns s = 4*lane..4*lane+3)
    float m = fmaxf(fmaxf(acc0, acc1), fmaxf(acc2, acc3));
    #pragma unroll
    for (int off = 32; off > 0; off >>= 1) m = fmaxf(m, __shfl_xor(m, off));
    float p0 = __builtin_amdgcn_exp2f((acc0 - m) * LOG2E);
    float p1 = __builtin_amdgcn_exp2f((acc1 - m) * LOG2E);
    float p2 = __builtin_amdgcn_exp2f((acc2 - m) * LOG2E);
    float p3 = __builtin_amdgcn_exp2f((acc3 - m) * LOG2E);
    float sum = (p0 + p1) + (p2 + p3);
    #pragma unroll
    for (int off = 32; off > 0; off >>= 1) sum += __shfl_xor(sum, off);
    float inv = __builtin_amdgcn_rcpf(sum);
    float4 p = make_float4(p0 * inv, p1 * inv, p2 * inv, p3 * inv);

    // score output (f32) + stash for ctx
    *(float4*)(out + (size_t)(b * TT + t0 + wid) * SS + 4 * lane) = p;
    *(float4*)(&w_s[wid][4 * lane]) = p;
    __syncthreads();

    // ctx[t][v] = sum_s w[t][s] * values[b][s][v]; thread owns v = tid, tid+256
    const float* vbase = values + (size_t)b * SS * DD;
    float c0[4] = {0.f, 0.f, 0.f, 0.f};
    float c1[4] = {0.f, 0.f, 0.f, 0.f};
    #pragma unroll 4
    for (int s = 0; s < SS; ++s) {
        float a0 = vbase[(size_t)s * DD + tid];
        float a1 = vbase[(size_t)s * DD + tid + 256];
        #pragma unroll
        for (int t = 0; t < 4; ++t) {
            float sc = w_s[t][s];
            c0[t] = fmaf(sc, a0, c0[t]);
            c1[t] = fmaf(sc, a1, c1[t]);
        }
    }
    float* octx = out + (size_t)BB * TT * SS;
    #pragma unroll
    for (int t = 0; t < 4; ++t) {
        size_t rowo = (size_t)(b * TT + t0 + t) * DD;
        octx[rowo + tid]       = c0[t];
        octx[rowo + tid + 256] = c1[t];
    }
}

// ---------------------------------------------------------------------------
extern "C" void kernel_launch(void* const* d_in, const int* in_sizes, int n_in,
                              void* d_out, int out_size, void* d_ws, size_t ws_size,
                              hipStream_t stream) {
    const float* query  = (const float*)d_in[0];  // (T,B,QD)
    const float* keys   = (const float*)d_in[1];  // (B,S,KD)
    const float* values = (const float*)d_in[2];  // (B,S,VD)
    const float* Wa     = (const float*)d_in[3];  // (KD, QD+KD)
    const float* va     = (const float*)d_in[4];  // (1, KD)
    float* out = (float*)d_out;

    float* eq  = (float*)d_ws;                    // 2048 x 512 f32 = 4 MB
    float* ekT = eq + (size_t)BB * TT * DD;       // 8 x 512 x 256 f32 = 4 MB

    dim3 gg(DD / 64, (BB * TT) / 64, 2);          // (8, 32, 2) — both GEMMs
    gemm_both<<<gg, 256, 0, stream>>>(query, keys, Wa, eq, ekT);

    attn_fused<<<dim3(TT / 4, BB), 256, 0, stream>>>(eq, ekT, va, values, out);
}

// Round 4
// 83.506 us; speedup vs baseline: 1.7330x; 1.2618x over previous
//
#include <hip/hip_runtime.h>
#include <hip/hip_bf16.h>

// Sizes (fixed by the problem)
#define TT   256   // t
#define BB   8     // batch
#define SS   256   // s
#define DD   512   // QD = KD = VD
#define C2LOG2E 2.8853900817779268f   // 2*log2(e)
#define LOG2E   1.4426950408889634f

// ---------------------------------------------------------------------------
// Both projection GEMMs in one 1D launch, XCD-pinned: b = blockIdx.x & 7 so
// all blocks of batch b run on XCD b (HW round-robins block idx across XCDs)
// and eq[b]/ekT[b] are written into that XCD's L2 for the attention kernel.
//   z=0: eq[b*T+t][k] = exp2(c * qp)        (row-major)
//   z=1: ekT[b][k][s] = exp2(c * kp)        (k-major / transposed)
// ---------------------------------------------------------------------------
__global__ __launch_bounds__(256) void gemm_both(const float* __restrict__ query,
                                                 const float* __restrict__ keys,
                                                 const float* __restrict__ Wa,
                                                 float* __restrict__ eq,
                                                 float* __restrict__ ekT) {
    const int idx = blockIdx.x;            // 512 blocks
    const int b   = idx & 7;
    const int r2  = idx >> 3;              // 0..63
    const int q   = r2 & 3;                // M-subtile within batch
    const int x   = (r2 >> 2) & 7;         // N-tile
    const int z   = r2 >> 5;               // 0 = query, 1 = keys

    const bool isQ = (z == 0);
    const float* A  = isQ ? query : keys;
    const float* Bm = isQ ? Wa : (Wa + DD);
    const int strideR = isQ ? BB * DD : DD;
    const int strideB = isQ ? DD : SS * DD;
    const int ldb = 2 * DD;

    __shared__ __align__(16) float As[32][68];
    __shared__ __align__(16) float Bs[32][68];
    const int tid = threadIdx.x;
    const int tx = tid & 15, ty = tid >> 4;
    const int tileN = x * 64;
    const int tileM = b * 256 + q * 64;

    const int lm = tid >> 2;      // 0..63: row within tile (staging)
    const int c4 = tid & 3;       // 0..3 : float4 column group

    const int mg = tileM + lm;
    const int r  = mg & 255, bidx = mg >> 8;
    const float* arow = A + (size_t)r * strideR + (size_t)bidx * strideB;
    const float* brow = Bm + (size_t)(tileN + lm) * ldb;

    float acc[4][4] = {};

    // prefetch chunk 0
    float4 a0 = *(const float4*)(arow + c4 * 4);
    float4 a1 = *(const float4*)(arow + 16 + c4 * 4);
    float4 b0 = *(const float4*)(brow + c4 * 4);
    float4 b1 = *(const float4*)(brow + 16 + c4 * 4);

    for (int kb = 0; kb < DD; kb += 32) {
        __syncthreads();
        As[c4*4+0][lm] = a0.x; As[c4*4+1][lm] = a0.y;
        As[c4*4+2][lm] = a0.z; As[c4*4+3][lm] = a0.w;
        As[16+c4*4+0][lm] = a1.x; As[16+c4*4+1][lm] = a1.y;
        As[16+c4*4+2][lm] = a1.z; As[16+c4*4+3][lm] = a1.w;
        Bs[c4*4+0][lm] = b0.x; Bs[c4*4+1][lm] = b0.y;
        Bs[c4*4+2][lm] = b0.z; Bs[c4*4+3][lm] = b0.w;
        Bs[16+c4*4+0][lm] = b1.x; Bs[16+c4*4+1][lm] = b1.y;
        Bs[16+c4*4+2][lm] = b1.z; Bs[16+c4*4+3][lm] = b1.w;
        __syncthreads();
        if (kb + 32 < DD) {   // prefetch next chunk while computing
            a0 = *(const float4*)(arow + kb + 32 + c4 * 4);
            a1 = *(const float4*)(arow + kb + 48 + c4 * 4);
            b0 = *(const float4*)(brow + kb + 32 + c4 * 4);
            b1 = *(const float4*)(brow + kb + 48 + c4 * 4);
        }
        #pragma unroll
        for (int kk = 0; kk < 32; ++kk) {
            float4 a4 = *(const float4*)&As[kk][ty * 4];
            float4 b4 = *(const float4*)&Bs[kk][tx * 4];
            float aa[4] = {a4.x, a4.y, a4.z, a4.w};
            float bb[4] = {b4.x, b4.y, b4.z, b4.w};
            #pragma unroll
            for (int i = 0; i < 4; ++i)
                #pragma unroll
                for (int j = 0; j < 4; ++j)
                    acc[i][j] = fmaf(aa[i], bb[j], acc[i][j]);
        }
    }

    if (isQ) {
        #pragma unroll
        for (int i = 0; i < 4; ++i) {
            float4 o;
            o.x = __builtin_amdgcn_exp2f(acc[i][0] * C2LOG2E);
            o.y = __builtin_amdgcn_exp2f(acc[i][1] * C2LOG2E);
            o.z = __builtin_amdgcn_exp2f(acc[i][2] * C2LOG2E);
            o.w = __builtin_amdgcn_exp2f(acc[i][3] * C2LOG2E);
            *(float4*)(eq + (size_t)(tileM + ty*4 + i) * DD + tileN + tx*4) = o;
        }
    } else {
        const int bb2 = tileM >> 8;
        const int s0  = (tileM & 255) + ty * 4;
        float* base = ekT + (size_t)bb2 * DD * SS;
        #pragma unroll
        for (int j = 0; j < 4; ++j) {
            const int n = tileN + tx * 4 + j;
            float4 o;
            o.x = __builtin_amdgcn_exp2f(acc[0][j] * C2LOG2E);
            o.y = __builtin_amdgcn_exp2f(acc[1][j] * C2LOG2E);
            o.z = __builtin_amdgcn_exp2f(acc[2][j] * C2LOG2E);
            o.w = __builtin_amdgcn_exp2f(acc[3][j] * C2LOG2E);
            *(float4*)(base + (size_t)n * SS + s0) = o;
        }
    }
}

// ---------------------------------------------------------------------------
// Fused attention. Block = 512 threads = 8 waves, covers (b, 4 t-rows).
// Wave w: kh = w>>2 (K-half), sq = w&3 (s-quarter). Each wave computes
// partial weight[4t][64s] over its K-half — disjoint ek reads (no redundancy),
// XCD-pinned so ekT[b]/values[b]/eq[b] are L2-resident.
// weight[t][s] = const + sum_k vb[k] * rcp(eq[t][k]*ekT[k][s] + 1)
// ---------------------------------------------------------------------------
__global__ __launch_bounds__(512) void attn_fused(const float* __restrict__ eq,
                                                  const float* __restrict__ ekT,
                                                  const float* __restrict__ va,
                                                  const float* __restrict__ values,
                                                  float* __restrict__ out) {
    __shared__ __align__(16) float eq_s[4][512];        // 8 KB
    __shared__ __align__(16) float vb_s[512];           // 2 KB
    __shared__ __align__(16) float wacc[2][4][4][64];   // 8 KB (kh,sq,t,lane)
    __shared__ __align__(16) float w_s[4][256];         // 4 KB
    __shared__ float red_m[4][4];                       // (sq, t)
    __shared__ float red_s[4][4];

    const int tid  = threadIdx.x;
    const int lane = tid & 63;
    const int w    = tid >> 6;          // wave 0..7
    const int sq   = w & 3;             // s-quarter
    const int kh   = w >> 2;            // k-half
    const int idx  = blockIdx.x;        // 512 blocks
    const int b    = idx & 7;           // XCD pin
    const int t0   = (idx >> 3) * 4;

    // Stage eq rows (4*512 floats) + vb = -2*va
    {
        const float4* qsrc = (const float4*)(eq + (size_t)(b * TT + t0) * DD);
        ((float4*)&eq_s[0][0])[tid] = qsrc[tid];
        if (tid < 128) {
            float4 v = ((const float4*)va)[tid];
            float4 nv = make_float4(-2.f*v.x, -2.f*v.y, -2.f*v.z, -2.f*v.w);
            ((float4*)vb_s)[tid] = nv;
        }
    }
    __syncthreads();

    const int kbase = kh * 256;
    const float* ekp = ekT + (size_t)b * DD * SS + sq * 64 + lane;
    const float4* eqr0 = (const float4*)&eq_s[0][kbase];
    const float4* eqr1 = (const float4*)&eq_s[1][kbase];
    const float4* eqr2 = (const float4*)&eq_s[2][kbase];
    const float4* eqr3 = (const float4*)&eq_s[3][kbase];
    const float4* vbr  = (const float4*)&vb_s[kbase];

    float acc0 = 0.f, acc1 = 0.f, acc2 = 0.f, acc3 = 0.f;

    #pragma unroll 4
    for (int kb = 0; kb < 256; kb += 4) {
        float ek0 = ekp[(size_t)(kbase + kb + 0) * SS];
        float ek1 = ekp[(size_t)(kbase + kb + 1) * SS];
        float ek2 = ekp[(size_t)(kbase + kb + 2) * SS];
        float ek3 = ekp[(size_t)(kbase + kb + 3) * SS];
        float4 e0 = eqr0[kb >> 2];
        float4 e1 = eqr1[kb >> 2];
        float4 e2 = eqr2[kb >> 2];
        float4 e3 = eqr3[kb >> 2];
        float4 vb = vbr[kb >> 2];
#define ASTEP(EC, EK, VC)                                                      \
        acc0 = fmaf(VC, __builtin_amdgcn_rcpf(fmaf(e0.EC, EK, 1.0f)), acc0);   \
        acc1 = fmaf(VC, __builtin_amdgcn_rcpf(fmaf(e1.EC, EK, 1.0f)), acc1);   \
        acc2 = fmaf(VC, __builtin_amdgcn_rcpf(fmaf(e2.EC, EK, 1.0f)), acc2);   \
        acc3 = fmaf(VC, __builtin_amdgcn_rcpf(fmaf(e3.EC, EK, 1.0f)), acc3);
        ASTEP(x, ek0, vb.x)
        ASTEP(y, ek1, vb.y)
        ASTEP(z, ek2, vb.z)
        ASTEP(w, ek3, vb.w)
#undef ASTEP
    }

    // Publish partials
    wacc[kh][sq][0][lane] = acc0;
    wacc[kh][sq][1][lane] = acc1;
    wacc[kh][sq][2][lane] = acc2;
    wacc[kh][sq][3][lane] = acc3;
    __syncthreads();

    float wt[4], p[4];
    if (kh == 0) {   // waves 0..3 finish softmax for their s-quarter
        #pragma unroll
        for (int t = 0; t < 4; ++t)
            wt[t] = wacc[0][sq][t][lane] + wacc[1][sq][t][lane];
        float mx[4];
        #pragma unroll
        for (int t = 0; t < 4; ++t) {
            float m = wt[t];
            #pragma unroll
            for (int off = 32; off > 0; off >>= 1) m = fmaxf(m, __shfl_xor(m, off));
            mx[t] = m;
        }
        if (lane == 0) {
            red_m[sq][0] = mx[0]; red_m[sq][1] = mx[1];
            red_m[sq][2] = mx[2]; red_m[sq][3] = mx[3];
        }
    }
    __syncthreads();
    if (kh == 0) {
        float sm[4];
        #pragma unroll
        for (int t = 0; t < 4; ++t) {
            float M = fmaxf(fmaxf(red_m[0][t], red_m[1][t]),
                            fmaxf(red_m[2][t], red_m[3][t]));
            p[t] = __builtin_amdgcn_exp2f((wt[t] - M) * LOG2E);
            float s = p[t];
            #pragma unroll
            for (int off = 32; off > 0; off >>= 1) s += __shfl_xor(s, off);
            sm[t] = s;
        }
        if (lane == 0) {
            red_s[sq][0] = sm[0]; red_s[sq][1] = sm[1];
            red_s[sq][2] = sm[2]; red_s[sq][3] = sm[3];
        }
    }
    __syncthreads();
    if (kh == 0) {
        #pragma unroll
        for (int t = 0; t < 4; ++t) {
            float inv = __builtin_amdgcn_rcpf(red_s[0][t] + red_s[1][t] +
                                              red_s[2][t] + red_s[3][t]);
            float sc = p[t] * inv;
            out[(size_t)(b * TT + t0 + t) * SS + sq * 64 + lane] = sc;
            w_s[t][sq * 64 + lane] = sc;
        }
    }
    __syncthreads();

    // ctx: 512 threads, thread owns column v = tid
    const float* vcol = values + (size_t)b * SS * DD + tid;
    const float4* wr0 = (const float4*)&w_s[0][0];
    const float4* wr1 = (const float4*)&w_s[1][0];
    const float4* wr2 = (const float4*)&w_s[2][0];
    const float4* wr3 = (const float4*)&w_s[3][0];
    float c0 = 0.f, c1 = 0.f, c2 = 0.f, c3 = 0.f;
    #pragma unroll 4
    for (int s = 0; s < SS; s += 4) {
        float4 w0 = wr0[s >> 2];
        float4 w1 = wr1[s >> 2];
        float4 w2 = wr2[s >> 2];
        float4 w3 = wr3[s >> 2];
        float v0 = vcol[(size_t)(s + 0) * DD];
        float v1 = vcol[(size_t)(s + 1) * DD];
        float v2 = vcol[(size_t)(s + 2) * DD];
        float v3 = vcol[(size_t)(s + 3) * DD];
        c0 = fmaf(w0.x, v0, c0); c1 = fmaf(w1.x, v0, c1);
        c2 = fmaf(w2.x, v0, c2); c3 = fmaf(w3.x, v0, c3);
        c0 = fmaf(w0.y, v1, c0); c1 = fmaf(w1.y, v1, c1);
        c2 = fmaf(w2.y, v1, c2); c3 = fmaf(w3.y, v1, c3);
        c0 = fmaf(w0.z, v2, c0); c1 = fmaf(w1.z, v2, c1);
        c2 = fmaf(w2.z, v2, c2); c3 = fmaf(w3.z, v2, c3);
        c0 = fmaf(w0.w, v3, c0); c1 = fmaf(w1.w, v3, c1);
        c2 = fmaf(w2.w, v3, c2); c3 = fmaf(w3.w, v3, c3);
    }
    float* octx = out + (size_t)BB * TT * SS + (size_t)(b * TT + t0) * DD + tid;
    octx[0 * DD] = c0; octx[1 * DD] = c1; octx[2 * DD] = c2; octx[3 * DD] = c3;
}

// ---------------------------------------------------------------------------
extern "C" void kernel_launch(void* const* d_in, const int* in_sizes, int n_in,
                              void* d_out, int out_size, void* d_ws, size_t ws_size,
                              hipStream_t stream) {
    const float* query  = (const float*)d_in[0];  // (T,B,QD)
    const float* keys   = (const float*)d_in[1];  // (B,S,KD)
    const float* values = (const float*)d_in[2];  // (B,S,VD)
    const float* Wa     = (const float*)d_in[3];  // (KD, QD+KD)
    const float* va     = (const float*)d_in[4];  // (1, KD)
    float* out = (float*)d_out;

    float* eq  = (float*)d_ws;                    // 2048 x 512 f32 = 4 MB
    float* ekT = eq + (size_t)BB * TT * DD;       // 8 x 512 x 256 f32 = 4 MB

    gemm_both<<<512, 256, 0, stream>>>(query, keys, Wa, eq, ekT);
    attn_fused<<<512, 512, 0, stream>>>(eq, ekT, va, values, out);
}

// Round 5
// 71.046 us; speedup vs baseline: 2.0370x; 1.1754x over previous
//
#include <hip/hip_runtime.h>
#include <hip/hip_bf16.h>

#define TT   256
#define BB   8
#define SS   256
#define DD   512
#define C2LOG2E 2.8853900817779268f   // 2*log2(e)
#define LOG2E   1.4426950408889634f

typedef __attribute__((ext_vector_type(8))) short bf16x8;
typedef __attribute__((ext_vector_type(4))) float f32x4;

__device__ __forceinline__ unsigned short f2bf(float f) {
    unsigned u = __builtin_bit_cast(unsigned, f);
    u += 0x7FFFu + ((u >> 16) & 1u);          // RNE (no NaN inputs here)
    return (unsigned short)(u >> 16);
}
__device__ __forceinline__ float bf2f(unsigned short h) {
    unsigned u = (unsigned)h << 16;
    return __builtin_bit_cast(float, u);
}

// ---------------------------------------------------------------------------
// MFMA projection GEMMs (both in one launch), split-bf16 (hi/lo, 3 terms).
// 512 blocks, XCD-pinned (b = idx&7). Block = 64x64 out tile, K=512, BK=64.
//   z=0: eq[b*256+t][n] = exp2(c * qp)
//   z=1: ekT[b][n][s]   = exp2(c * kp)   (transposed via LDS)
// ---------------------------------------------------------------------------
#define LDK 72   // padded row stride (elements); 144 B = 16B-multiple
__global__ __launch_bounds__(256) void gemm_mfma(const float* __restrict__ query,
                                                 const float* __restrict__ keys,
                                                 const float* __restrict__ Wa,
                                                 float* __restrict__ eq,
                                                 float* __restrict__ ekT) {
    __shared__ __align__(16) unsigned char smem[4 * 64 * LDK * 2];  // 36 KB
    unsigned short* sAh = (unsigned short*)smem;
    unsigned short* sAl = sAh + 64 * LDK;
    unsigned short* sBh = sAl + 64 * LDK;
    unsigned short* sBl = sBh + 64 * LDK;
    float* Cst = (float*)smem;                // reused for z=1 transpose

    const int idx = blockIdx.x;
    const int b   = idx & 7;
    const int r2  = idx >> 3;
    const int q   = r2 & 3;
    const int x   = (r2 >> 2) & 7;
    const int z   = r2 >> 5;
    const bool isQ = (z == 0);

    const float* A  = isQ ? query : keys;
    const int strideR = isQ ? BB * DD : DD;
    const int strideB = isQ ? DD : SS * DD;
    const float* Bsrc = Wa + (isQ ? 0 : DD);

    const int tileN = x * 64;

    const int tid = threadIdx.x;
    const int rb  = tid >> 4;       // 0..15 base row
    const int c4  = tid & 15;       // float4 column group (cols c4*4..+3)

    const float* arow0 = A + (size_t)b * strideB + (size_t)(q * 64) * strideR;
    const float* brow0 = Bsrc + (size_t)tileN * (2 * DD);

    float4 av[4], bv[4];
    #pragma unroll
    for (int i = 0; i < 4; ++i) {
        av[i] = *(const float4*)(arow0 + (size_t)(rb + 16*i) * strideR + c4 * 4);
        bv[i] = *(const float4*)(brow0 + (size_t)(rb + 16*i) * (2*DD) + c4 * 4);
    }

    const int w    = tid >> 6;             // wave 0..3
    const int lane = tid & 63;
    const int wm   = (w >> 1) * 32;
    const int wn   = (w & 1) * 32;
    const int r16  = lane & 15;
    const int k8   = (lane >> 4) * 8;

    f32x4 acc[2][2] = {};

    for (int kb = 0; kb < DD; kb += 64) {
        __syncthreads();
        #pragma unroll
        for (int i = 0; i < 4; ++i) {
            const int row = rb + 16 * i;
            float4 a = av[i], bq = bv[i];
            ushort4 ah, al, bh, bl;
            ah.x = f2bf(a.x); al.x = f2bf(a.x - bf2f(ah.x));
            ah.y = f2bf(a.y); al.y = f2bf(a.y - bf2f(ah.y));
            ah.z = f2bf(a.z); al.z = f2bf(a.z - bf2f(ah.z));
            ah.w = f2bf(a.w); al.w = f2bf(a.w - bf2f(ah.w));
            bh.x = f2bf(bq.x); bl.x = f2bf(bq.x - bf2f(bh.x));
            bh.y = f2bf(bq.y); bl.y = f2bf(bq.y - bf2f(bh.y));
            bh.z = f2bf(bq.z); bl.z = f2bf(bq.z - bf2f(bh.z));
            bh.w = f2bf(bq.w); bl.w = f2bf(bq.w - bf2f(bh.w));
            *(ushort4*)(sAh + row * LDK + c4 * 4) = ah;
            *(ushort4*)(sAl + row * LDK + c4 * 4) = al;
            *(ushort4*)(sBh + row * LDK + c4 * 4) = bh;
            *(ushort4*)(sBl + row * LDK + c4 * 4) = bl;
        }
        __syncthreads();
        if (kb + 64 < DD) {
            #pragma unroll
            for (int i = 0; i < 4; ++i) {
                av[i] = *(const float4*)(arow0 + (size_t)(rb + 16*i) * strideR + kb + 64 + c4 * 4);
                bv[i] = *(const float4*)(brow0 + (size_t)(rb + 16*i) * (2*DD) + kb + 64 + c4 * 4);
            }
        }
        #pragma unroll
        for (int ks = 0; ks < 2; ++ks) {
            const int ko = ks * 32 + k8;
            bf16x8 a_h[2], a_l[2], b_h[2], b_l[2];
            #pragma unroll
            for (int mt = 0; mt < 2; ++mt) {
                a_h[mt] = *(const bf16x8*)(sAh + (wm + mt*16 + r16) * LDK + ko);
                a_l[mt] = *(const bf16x8*)(sAl + (wm + mt*16 + r16) * LDK + ko);
            }
            #pragma unroll
            for (int nt = 0; nt < 2; ++nt) {
                b_h[nt] = *(const bf16x8*)(sBh + (wn + nt*16 + r16) * LDK + ko);
                b_l[nt] = *(const bf16x8*)(sBl + (wn + nt*16 + r16) * LDK + ko);
            }
            #pragma unroll
            for (int mt = 0; mt < 2; ++mt)
                #pragma unroll
                for (int nt = 0; nt < 2; ++nt) {
                    acc[mt][nt] = __builtin_amdgcn_mfma_f32_16x16x32_bf16(a_h[mt], b_h[nt], acc[mt][nt], 0, 0, 0);
                    acc[mt][nt] = __builtin_amdgcn_mfma_f32_16x16x32_bf16(a_h[mt], b_l[nt], acc[mt][nt], 0, 0, 0);
                    acc[mt][nt] = __builtin_amdgcn_mfma_f32_16x16x32_bf16(a_l[mt], b_h[nt], acc[mt][nt], 0, 0, 0);
                }
        }
    }

    // Epilogue: C/D layout col = lane&15, row = (lane>>4)*4 + reg  [verified]
    const int crow = (lane >> 4) * 4;
    if (isQ) {
        #pragma unroll
        for (int mt = 0; mt < 2; ++mt)
            #pragma unroll
            for (int nt = 0; nt < 2; ++nt)
                #pragma unroll
                for (int i = 0; i < 4; ++i) {
                    const int m = b * 256 + q * 64 + wm + mt*16 + crow + i;
                    const int n = tileN + wn + nt*16 + r16;
                    eq[(size_t)m * DD + n] = __builtin_amdgcn_exp2f(acc[mt][nt][i] * C2LOG2E);
                }
    } else {
        __syncthreads();
        #pragma unroll
        for (int mt = 0; mt < 2; ++mt)
            #pragma unroll
            for (int nt = 0; nt < 2; ++nt)
                #pragma unroll
                for (int i = 0; i < 4; ++i)
                    Cst[(wm + mt*16 + crow + i) * 69 + wn + nt*16 + r16] =
                        __builtin_amdgcn_exp2f(acc[mt][nt][i] * C2LOG2E);
        __syncthreads();
        const int n  = tid & 63;
        const int sg = tid >> 6;
        float* dst = ekT + (size_t)b * DD * SS + (size_t)(tileN + n) * SS + q * 64 + sg * 16;
        #pragma unroll
        for (int j4 = 0; j4 < 4; ++j4) {
            float4 o;
            o.x = Cst[(sg*16 + j4*4 + 0) * 69 + n];
            o.y = Cst[(sg*16 + j4*4 + 1) * 69 + n];
            o.z = Cst[(sg*16 + j4*4 + 2) * 69 + n];
            o.w = Cst[(sg*16 + j4*4 + 3) * 69 + n];
            *(float4*)(dst + j4 * 4) = o;
        }
    }
}

// ---------------------------------------------------------------------------
// Fused attention. 512 blocks x 1024 threads (16 waves), XCD-pinned.
// Block = (b, 4 t-rows). Wave w: kq = w&3 (k-quarter), sq = w>>2 (s-quarter).
// Per lane: 4 t-accumulators over its 128-k quarter; ekT[b] read exactly once
// per block. weight[t][s] = const + sum_k vb[k]*rcp(eq[t][k]*ekT[k][s]+1).
// ---------------------------------------------------------------------------
__global__ __launch_bounds__(1024, 8) void attn_fused(const float* __restrict__ eq,
                                                      const float* __restrict__ ekT,
                                                      const float* __restrict__ va,
                                                      const float* __restrict__ values,
                                                      float* __restrict__ out) {
    __shared__ __align__(16) float eq_s[4][512];     // 8 KB
    __shared__ __align__(16) float vb_s[512];        // 2 KB
    __shared__ __align__(16) float wacc[4][4][256];  // [t][kq][s] 16 KB
    __shared__ __align__(16) float w_s[4][256];      // 4 KB
    __shared__ float red_m[4][4];                    // [sq][t]
    __shared__ float red_s[4][4];

    const int tid  = threadIdx.x;
    const int lane = tid & 63;
    const int w    = tid >> 6;          // 0..15
    const int kq   = w & 3;
    const int sq   = w >> 2;
    const int idx  = blockIdx.x;
    const int b    = idx & 7;           // XCD pin
    const int t0   = (idx >> 3) * 4;

    if (tid < 512) {
        const float4* qsrc = (const float4*)(eq + (size_t)(b * TT + t0) * DD);
        ((float4*)&eq_s[0][0])[tid] = qsrc[tid];
    } else if (tid < 640) {
        const int i = tid - 512;
        float4 v = ((const float4*)va)[i];
        ((float4*)vb_s)[i] = make_float4(-2.f*v.x, -2.f*v.y, -2.f*v.z, -2.f*v.w);
    }
    __syncthreads();

    const int kbase = kq * 128;
    const int s     = sq * 64 + lane;
    const float* ekp = ekT + (size_t)b * DD * SS + (size_t)kbase * SS + s;
    const float4* eqr0 = (const float4*)&eq_s[0][kbase];
    const float4* eqr1 = (const float4*)&eq_s[1][kbase];
    const float4* eqr2 = (const float4*)&eq_s[2][kbase];
    const float4* eqr3 = (const float4*)&eq_s[3][kbase];
    const float4* vbr  = (const float4*)&vb_s[kbase];

    float acc0 = 0.f, acc1 = 0.f, acc2 = 0.f, acc3 = 0.f;

    #pragma unroll 4
    for (int kb = 0; kb < 128; kb += 4) {
        float ek0 = ekp[(size_t)(kb + 0) * SS];
        float ek1 = ekp[(size_t)(kb + 1) * SS];
        float ek2 = ekp[(size_t)(kb + 2) * SS];
        float ek3 = ekp[(size_t)(kb + 3) * SS];
        float4 e0 = eqr0[kb >> 2];
        float4 e1 = eqr1[kb >> 2];
        float4 e2 = eqr2[kb >> 2];
        float4 e3 = eqr3[kb >> 2];
        float4 vb = vbr[kb >> 2];
#define ASTEP(EC, EK, VC)                                                      \
        acc0 = fmaf(VC, __builtin_amdgcn_rcpf(fmaf(e0.EC, EK, 1.0f)), acc0);   \
        acc1 = fmaf(VC, __builtin_amdgcn_rcpf(fmaf(e1.EC, EK, 1.0f)), acc1);   \
        acc2 = fmaf(VC, __builtin_amdgcn_rcpf(fmaf(e2.EC, EK, 1.0f)), acc2);   \
        acc3 = fmaf(VC, __builtin_amdgcn_rcpf(fmaf(e3.EC, EK, 1.0f)), acc3);
        ASTEP(x, ek0, vb.x)
        ASTEP(y, ek1, vb.y)
        ASTEP(z, ek2, vb.z)
        ASTEP(w, ek3, vb.w)
#undef ASTEP
    }

    wacc[0][kq][s] = acc0;
    wacc[1][kq][s] = acc1;
    wacc[2][kq][s] = acc2;
    wacc[3][kq][s] = acc3;
    __syncthreads();

    float wt[4], p[4];
    if (kq == 0) {
        #pragma unroll
        for (int t = 0; t < 4; ++t)
            wt[t] = (wacc[t][0][s] + wacc[t][1][s]) + (wacc[t][2][s] + wacc[t][3][s]);
        #pragma unroll
        for (int t = 0; t < 4; ++t) {
            float m = wt[t];
            #pragma unroll
            for (int off = 32; off > 0; off >>= 1) m = fmaxf(m, __shfl_xor(m, off));
            if (lane == 0) red_m[sq][t] = m;
        }
    }
    __syncthreads();
    if (kq == 0) {
        #pragma unroll
        for (int t = 0; t < 4; ++t) {
            float M = fmaxf(fmaxf(red_m[0][t], red_m[1][t]),
                            fmaxf(red_m[2][t], red_m[3][t]));
            p[t] = __builtin_amdgcn_exp2f((wt[t] - M) * LOG2E);
            float sm = p[t];
            #pragma unroll
            for (int off = 32; off > 0; off >>= 1) sm += __shfl_xor(sm, off);
            if (lane == 0) red_s[sq][t] = sm;
        }
    }
    __syncthreads();
    if (kq == 0) {
        #pragma unroll
        for (int t = 0; t < 4; ++t) {
            float inv = __builtin_amdgcn_rcpf((red_s[0][t] + red_s[1][t]) +
                                              (red_s[2][t] + red_s[3][t]));
            float sc = p[t] * inv;
            out[(size_t)(b * TT + t0 + t) * SS + s] = sc;
            w_s[t][s] = sc;
        }
    }
    __syncthreads();

    // ctx: v-column = tid&511, t-pair = tid>>9
    const int v  = tid & 511;
    const int th = tid >> 9;
    const float* vcol = values + (size_t)b * SS * DD + v;
    const float4* wr0 = (const float4*)&w_s[th * 2][0];
    const float4* wr1 = (const float4*)&w_s[th * 2 + 1][0];
    float c0 = 0.f, c1 = 0.f;
    #pragma unroll 4
    for (int ss = 0; ss < SS; ss += 4) {
        float4 w0 = wr0[ss >> 2];
        float4 w1 = wr1[ss >> 2];
        float v0 = vcol[(size_t)(ss + 0) * DD];
        float v1 = vcol[(size_t)(ss + 1) * DD];
        float v2 = vcol[(size_t)(ss + 2) * DD];
        float v3 = vcol[(size_t)(ss + 3) * DD];
        c0 = fmaf(w0.x, v0, c0); c1 = fmaf(w1.x, v0, c1);
        c0 = fmaf(w0.y, v1, c0); c1 = fmaf(w1.y, v1, c1);
        c0 = fmaf(w0.z, v2, c0); c1 = fmaf(w1.z, v2, c1);
        c0 = fmaf(w0.w, v3, c0); c1 = fmaf(w1.w, v3, c1);
    }
    float* octx = out + (size_t)BB * TT * SS + (size_t)(b * TT + t0 + th * 2) * DD + v;
    octx[0]  = c0;
    octx[DD] = c1;
}

// ---------------------------------------------------------------------------
extern "C" void kernel_launch(void* const* d_in, const int* in_sizes, int n_in,
                              void* d_out, int out_size, void* d_ws, size_t ws_size,
                              hipStream_t stream) {
    const float* query  = (const float*)d_in[0];  // (T,B,QD)
    const float* keys   = (const float*)d_in[1];  // (B,S,KD)
    const float* values = (const float*)d_in[2];  // (B,S,VD)
    const float* Wa     = (const float*)d_in[3];  // (KD, QD+KD)
    const float* va     = (const float*)d_in[4];  // (1, KD)
    float* out = (float*)d_out;

    float* eq  = (float*)d_ws;                    // 2048 x 512 f32 = 4 MB
    float* ekT = eq + (size_t)BB * TT * DD;       // 8 x 512 x 256 f32 = 4 MB

    gemm_mfma<<<512, 256, 0, stream>>>(query, keys, Wa, eq, ekT);
    attn_fused<<<512, 1024, 0, stream>>>(eq, ekT, va, values, out);
}